// Round 1
// baseline (229.215 us; speedup 1.0000x reference)
//
#include <hip/hip_runtime.h>

#define D 640
#define HID 64
#define NITER 64
#define ROWS 4           // rows per block == waves per block
#define BLOCK 256

__device__ __forceinline__ float wave_max(float v) {
#pragma unroll
    for (int off = 32; off; off >>= 1) v = fmaxf(v, __shfl_xor(v, off));
    return v;
}
__device__ __forceinline__ float wave_sum(float v) {
#pragma unroll
    for (int off = 32; off; off >>= 1) v += __shfl_xor(v, off);
    return v;
}

__global__ __launch_bounds__(BLOCK) void dimmask_kernel(
    const float* __restrict__ x, const float* __restrict__ W1,
    const float* __restrict__ b1, const float* __restrict__ W2,
    const float* __restrict__ b2, float* __restrict__ out)
{
    constexpr float EPS   = 1e-7f;
    constexpr float INV_T = 1.0f / 0.07f;
    constexpr float LOG2E = 1.4426950408889634f;

    __shared__ float lds_x[ROWS][D];          // 10 KB
    __shared__ float lds_part[4][ROWS][HID];  // 4 KB
    __shared__ float lds_hid[ROWS][HID];      // 1 KB
    __shared__ float lds_ht[ROWS][D];         // 10 KB

    const int tid  = threadIdx.x;
    const int row0 = blockIdx.x * ROWS;

    // ---- stage x rows into LDS (coalesced float4) ----
    {
        const float4* xv  = (const float4*)(x + (size_t)row0 * D);
        float4*       lxv = (float4*)(&lds_x[0][0]);
        for (int i = tid; i < ROWS * D / 4; i += BLOCK) lxv[i] = xv[i];
    }
    __syncthreads();

    // ---- GEMM1: hid[r][k] = relu(sum_t x[r][t]*W1[t][k] + b1[k]) ----
    // thread = (k = lane, c = wave); W1 read once per block, coalesced across k
    {
        const int k = tid & 63, c = tid >> 6;
        float acc[ROWS] = {0.f, 0.f, 0.f, 0.f};
        const int t0 = c * (D / 4);
#pragma unroll 4
        for (int t = t0; t < t0 + D / 4; ++t) {
            float w = W1[t * HID + k];
#pragma unroll
            for (int r = 0; r < ROWS; ++r) acc[r] += lds_x[r][t] * w;
        }
#pragma unroll
        for (int r = 0; r < ROWS; ++r) lds_part[c][r][k] = acc[r];
    }
    __syncthreads();
    {
        const int r = tid >> 6, k = tid & 63;  // 4*64 == 256 threads exactly
        float s = lds_part[0][r][k] + lds_part[1][r][k]
                + lds_part[2][r][k] + lds_part[3][r][k] + b1[k];
        lds_hid[r][k] = fmaxf(s, 0.f);
    }
    __syncthreads();

    // ---- GEMM2: ht[r][j] = -(sum_k hid[r][k]*W2[k][j] + b2[j]) * log2e/T ----
    // W2 read once per block, coalesced across tid
    for (int j = tid; j < D; j += BLOCK) {
        float acc[ROWS] = {0.f, 0.f, 0.f, 0.f};
#pragma unroll 8
        for (int k = 0; k < HID; ++k) {
            float w = W2[k * D + j];
#pragma unroll
            for (int r = 0; r < ROWS; ++r) acc[r] += lds_hid[r][k] * w;
        }
        float bb = b2[j];
#pragma unroll
        for (int r = 0; r < ROWS; ++r)
            lds_ht[r][j] = -(acc[r] + bb) * (LOG2E * INV_T);
    }
    __syncthreads();

    // ---- Phase B: one wave per row, 10 elements/lane in registers ----
    const int r = tid >> 6, l = tid & 63;
    float ht[10], hh[10];
#pragma unroll
    for (int u = 0; u < 10; ++u) { ht[u] = lds_ht[r][l + 64 * u]; hh[u] = 0.f; }

    for (int it = 0; it < NITER; ++it) {
        float m[10], z[10];
        float mx = -3.0e38f;
#pragma unroll
        for (int u = 0; u < 10; ++u) {
            m[u] = fmaxf(1.f - hh[u], 0.f);                       // guard vs 1-ulp overshoot
            z[u] = fmaf(__builtin_amdgcn_logf(m[u] + EPS), INV_T, ht[u]);  // log2 domain
            mx = fmaxf(mx, z[u]);
        }
        mx = wave_max(mx);
        float e[10], s = 0.f;
#pragma unroll
        for (int u = 0; u < 10; ++u) {
            e[u] = __builtin_amdgcn_exp2f(z[u] - mx);
            s += e[u];
        }
        s = wave_sum(s);
        float rs = __builtin_amdgcn_rcpf(s);
#pragma unroll
        for (int u = 0; u < 10; ++u)
            hh[u] = fmaf(e[u] * m[u], rs, hh[u]);
    }

    // ---- epilogue: out = (1 - hhat) * x ----
    float* orow = out + (size_t)(row0 + r) * D;
#pragma unroll
    for (int u = 0; u < 10; ++u) {
        int j = l + 64 * u;
        orow[j] = (1.f - hh[u]) * lds_x[r][j];
    }
}

extern "C" void kernel_launch(void* const* d_in, const int* in_sizes, int n_in,
                              void* d_out, int out_size, void* d_ws, size_t ws_size,
                              hipStream_t stream) {
    const float* x  = (const float*)d_in[0];
    const float* W1 = (const float*)d_in[1];
    const float* b1 = (const float*)d_in[2];
    const float* W2 = (const float*)d_in[3];
    const float* b2 = (const float*)d_in[4];
    float* out = (float*)d_out;

    const int B = in_sizes[0] / D;            // 8192
    dim3 grid(B / ROWS), block(BLOCK);
    hipLaunchKernelGGL(dimmask_kernel, grid, block, 0, stream, x, W1, b1, W2, b2, out);
}

// Round 2
// 207.760 us; speedup vs baseline: 1.1033x; 1.1033x over previous
//
#include <hip/hip_runtime.h>

#define D 640
#define HID 64
#define NITER 64
#define ROWS 4           // rows per block == waves per block
#define BLOCK 256

__device__ __forceinline__ float wave_sum(float v) {
#pragma unroll
    for (int off = 32; off; off >>= 1) v += __shfl_xor(v, off);
    return v;
}

// (1-y)^(100/7), Taylor in y, valid |y| <= ~0.04 (used for y <= 2^-5)
__device__ __forceinline__ float pow_main(float y) {
    float p = -2255.638f;
    p = fmaf(p, y, 1096.4908f);
    p = fmaf(p, y, -388.62974f);
    p = fmaf(p, y, 94.897959f);
    p = fmaf(p, y, -14.2857143f);
    p = fmaf(p, y, 1.0f);
    return p;
}
// (1-y)^(2/7), Taylor in y, y in [0,1]; coarse near y=1 but multiplied by f^14->0 there
__device__ __forceinline__ float pow_frac(float y) {
    float q = -0.0293926f;
    q = fmaf(q, y, -0.0395668f);
    q = fmaf(q, y, -0.0583090f);
    q = fmaf(q, y, -0.1020408f);
    q = fmaf(q, y, -0.2857143f);
    q = fmaf(q, y, 1.0f);
    return q;
}

__global__ __launch_bounds__(BLOCK) void dimmask_kernel(
    const float* __restrict__ x, const float* __restrict__ W1,
    const float* __restrict__ b1, const float* __restrict__ W2,
    const float* __restrict__ b2, float* __restrict__ out)
{
    constexpr float INV_T = 1.0f / 0.07f;
    constexpr float LOG2E = 1.4426950408889634f;
    constexpr float TEMP  = 0.07f;

    // lds_a: holds x rows for GEMM1, then reused for ht (x is reloaded in epilogue)
    __shared__ float lds_a[ROWS][D];          // 10 KB
    __shared__ float lds_part[4][ROWS][HID];  // 4 KB
    __shared__ float lds_hid[ROWS][HID];      // 1 KB

    const int tid  = threadIdx.x;
    const int row0 = blockIdx.x * ROWS;

    // ---- stage x rows into LDS (coalesced float4) ----
    {
        const float4* xv  = (const float4*)(x + (size_t)row0 * D);
        float4*       lxv = (float4*)(&lds_a[0][0]);
        for (int i = tid; i < ROWS * D / 4; i += BLOCK) lxv[i] = xv[i];
    }
    __syncthreads();

    // ---- GEMM1: hid[r][k] = relu(sum_t x[r][t]*W1[t][k] + b1[k]) ----
    {
        const int k = tid & 63, c = tid >> 6;
        float acc[ROWS] = {0.f, 0.f, 0.f, 0.f};
        const int t0 = c * (D / 4);
#pragma unroll 4
        for (int t = t0; t < t0 + D / 4; ++t) {
            float w = W1[t * HID + k];
#pragma unroll
            for (int r = 0; r < ROWS; ++r) acc[r] += lds_a[r][t] * w;
        }
#pragma unroll
        for (int r = 0; r < ROWS; ++r) lds_part[c][r][k] = acc[r];
    }
    __syncthreads();
    {
        const int r = tid >> 6, k = tid & 63;
        float s = lds_part[0][r][k] + lds_part[1][r][k]
                + lds_part[2][r][k] + lds_part[3][r][k] + b1[k];
        lds_hid[r][k] = fmaxf(s, 0.f);
    }
    __syncthreads();

    // ---- GEMM2: ht[r][j] = -(h)*log2e/T  written over dead x in lds_a ----
    for (int j = tid; j < D; j += BLOCK) {
        float acc[ROWS] = {0.f, 0.f, 0.f, 0.f};
#pragma unroll 8
        for (int k = 0; k < HID; ++k) {
            float w = W2[k * D + j];
#pragma unroll
            for (int r = 0; r < ROWS; ++r) acc[r] += lds_hid[r][k] * w;
        }
        float bb = b2[j];
#pragma unroll
        for (int r = 0; r < ROWS; ++r)
            lds_a[r][j] = fminf(-(acc[r] + bb) * (LOG2E * INV_T), 120.0f);
    }
    __syncthreads();

    // ---- Phase B: one wave per row; w-domain recurrence, no transcendentals ----
    const int r = tid >> 6, l = tid & 63;
    float E[10], w[10];
#pragma unroll
    for (int u = 0; u < 10; ++u) {
        E[u] = __builtin_amdgcn_exp2f(lds_a[r][l + 64 * u]);  // exp(-h/T)
        w[u] = 1.0f;                                          // m^(1/T), m=1
    }

    for (int it = 0; it < NITER; ++it) {
        float e[10], s = 0.f;
#pragma unroll
        for (int u = 0; u < 10; ++u) { e[u] = w[u] * E[u]; s += e[u]; }
        s = wave_sum(s);
        float rs = __builtin_amdgcn_rcpf(s);
#pragma unroll
        for (int u = 0; u < 10; ++u) {
            float y = e[u] * rs;                 // yhat
            if (__any(y > 0.03125f)) {
                float f  = fmaxf(fmaf(-e[u], rs, 1.0f), 0.f);   // 1-y, guarded
                float f2 = f * f, f4 = f2 * f2, f8 = f4 * f4;
                float f14 = f8 * f4 * f2;
                w[u] *= f14 * pow_frac(y);       // f^14 * f^(2/7) = f^(100/7)
            } else {
                w[u] *= pow_main(y);             // (1-y)^(100/7) Taylor
            }
        }
    }

    // ---- epilogue: m = w^T; out = m * x (x reloaded from global, coalesced) ----
    const float* xrow = x + (size_t)(row0 + r) * D;
    float* orow = out + (size_t)(row0 + r) * D;
#pragma unroll
    for (int u = 0; u < 10; ++u) {
        int j = l + 64 * u;
        float m = __builtin_amdgcn_exp2f(TEMP * __builtin_amdgcn_logf(w[u]));
        orow[j] = m * xrow[j];
    }
}

extern "C" void kernel_launch(void* const* d_in, const int* in_sizes, int n_in,
                              void* d_out, int out_size, void* d_ws, size_t ws_size,
                              hipStream_t stream) {
    const float* x  = (const float*)d_in[0];
    const float* W1 = (const float*)d_in[1];
    const float* b1 = (const float*)d_in[2];
    const float* W2 = (const float*)d_in[3];
    const float* b2 = (const float*)d_in[4];
    float* out = (float*)d_out;

    const int B = in_sizes[0] / D;            // 8192
    dim3 grid(B / ROWS), block(BLOCK);
    hipLaunchKernelGGL(dimmask_kernel, grid, block, 0, stream, x, W1, b1, W2, b2, out);
}